// Round 1
// baseline (349.264 us; speedup 1.0000x reference)
//
#include <hip/hip_runtime.h>

typedef _Float16 half8 __attribute__((ext_vector_type(8)));
typedef float f32x4 __attribute__((ext_vector_type(4)));

#define HID 512
#define CHUNK_L 64
#define NCHUNK 2048

// Repack conv_w [O=512][I=512][tap=2] fp32 -> Wt[n=512][k=1024] fp16,
// k = tap*512 + i  (k-contiguous rows => MFMA B-fragment loads are 16B contiguous)
__global__ void prep_w_kernel(const float* __restrict__ conv_w, _Float16* __restrict__ Wt) {
  int idx = blockIdx.x * blockDim.x + threadIdx.x;
  if (idx >= HID * HID * 2) return;
  int n = idx >> 10;
  int k = idx & 1023;
  int tap = k >> 9;
  int i = k & 511;
  Wt[idx] = (_Float16)conv_w[n * 1024 + i * 2 + tap];
}

// One block per chunk. 512 threads = 8 waves.
// LDS swizzle: byte_in_row ^= ((row & 7) << 4)  -- permutes 16B granules within
// each 128B stripe; applied identically on every read & write of a tile.
__global__ __launch_bounds__(512) void fused_kernel(
    const float* __restrict__ x, const _Float16* __restrict__ Wt,
    const float* __restrict__ conv_b, const float* __restrict__ ln_g,
    const float* __restrict__ ln_b, float* __restrict__ out) {

  // xs: storage row s holds x[s-1]; rows 0 and 65 are zero (conv boundary).
  // After the scores phase xs is dead and is reused as ctT[512][64].
  __shared__ __align__(16) _Float16 xs[66 * 512];
  __shared__ __align__(16) _Float16 ct[64 * 512];
  __shared__ __align__(16) float sc[64 * 68];
  __shared__ __align__(16) _Float16 P[64 * 64];
  __shared__ float rowpart[64 * 8 * 2];
  __shared__ float mustat[64 * 2];

  const int tid = threadIdx.x;
  const int blk = blockIdx.x;
  const int w = tid >> 6;     // wave id 0..7
  const int l = tid & 63;     // lane
  const int l15 = l & 15;
  const int lq = l >> 4;

  char* xsb = (char*)xs;
  char* ctb = (char*)ct;
  char* Pb  = (char*)P;

  const f32x4 fzero = {0.f, 0.f, 0.f, 0.f};

  // ---------- Phase 0: stage x chunk -> LDS fp16 (swizzled), zero guard rows
  {
    const float* xg = x + (size_t)blk * (CHUNK_L * HID);
#pragma unroll
    for (int i = 0; i < 8; ++i) {
      int j = tid + i * 512;          // 0..4095 : 64 rows x 64 groups of 8 floats
      int t = j >> 6;
      int d8 = j & 63;
      const float4* src = (const float4*)(xg + t * HID + d8 * 8);
      float4 f0 = src[0];
      float4 f1 = src[1];
      half8 h;
      h[0] = (_Float16)f0.x; h[1] = (_Float16)f0.y; h[2] = (_Float16)f0.z; h[3] = (_Float16)f0.w;
      h[4] = (_Float16)f1.x; h[5] = (_Float16)f1.y; h[6] = (_Float16)f1.z; h[7] = (_Float16)f1.w;
      int srow = t + 1;
      *(half8*)(xsb + srow * 1024 + ((d8 * 16) ^ ((srow & 7) << 4))) = h;
    }
    if (tid < 128) {
      int r = (tid < 64) ? 0 : 65;
      int g = tid & 63;
      half8 z = {0, 0, 0, 0, 0, 0, 0, 0};
      *(half8*)(xsb + r * 1024 + g * 16) = z;   // zeros: swizzle-invariant
    }
  }
  __syncthreads();

  // ---------- Phase 1: conv GEMM  ct = relu(A[64x1024] @ W[1024x512] + b)
  // A[t][k] = (k<512) ? x[t-1][k] : x[t+1][k-512]  -> xs storage rows t / t+2.
  {
    f32x4 acc[4][4];
#pragma unroll
    for (int mi = 0; mi < 4; ++mi)
#pragma unroll
      for (int ni = 0; ni < 4; ++ni) acc[mi][ni] = fzero;

    for (int ks = 0; ks < 32; ++ks) {
      const int kc = (ks & 15) * 32 + lq * 8;      // column within xs (halves)
      const int rowoff = (ks < 16) ? 0 : 2;
      half8 a[4], b[4];
#pragma unroll
      for (int mi = 0; mi < 4; ++mi) {
        int srow = mi * 16 + l15 + rowoff;
        a[mi] = *(const half8*)(xsb + srow * 1024 + ((kc * 2) ^ ((srow & 7) << 4)));
      }
#pragma unroll
      for (int ni = 0; ni < 4; ++ni) {
        int n = w * 64 + ni * 16 + l15;
        b[ni] = *(const half8*)(Wt + n * 1024 + ks * 32 + lq * 8);
      }
#pragma unroll
      for (int mi = 0; mi < 4; ++mi)
#pragma unroll
        for (int ni = 0; ni < 4; ++ni)
          acc[mi][ni] = __builtin_amdgcn_mfma_f32_16x16x32_f16(a[mi], b[ni], acc[mi][ni], 0, 0, 0);
    }

    // epilogue: + bias, relu, store fp16 to ct (swizzled)
    float cb[4];
#pragma unroll
    for (int ni = 0; ni < 4; ++ni) cb[ni] = conv_b[w * 64 + ni * 16 + l15];
#pragma unroll
    for (int mi = 0; mi < 4; ++mi)
#pragma unroll
      for (int ni = 0; ni < 4; ++ni)
#pragma unroll
        for (int r = 0; r < 4; ++r) {
          int t = mi * 16 + lq * 4 + r;
          int n = w * 64 + ni * 16 + l15;
          float v = acc[mi][ni][r] + cb[ni];
          v = fmaxf(v, 0.f);
          *(_Float16*)(ctb + t * 1024 + ((2 * n) ^ ((t & 7) << 4))) = (_Float16)v;
        }
  }
  __syncthreads();

  // ---------- Phase 2: scores = cx @ ct^T / sqrt(D)   [64 q][64 key]
  {
    const int qt = w >> 1;             // query tile 0..3
    const int kb = (w & 1) * 2;        // first of two key tiles
    f32x4 s0 = fzero, s1 = fzero;
    for (int ks = 0; ks < 16; ++ks) {
      int kc = ks * 32 + lq * 8;
      int srow = qt * 16 + l15 + 1;    // x[q] lives at storage row q+1
      half8 a = *(const half8*)(xsb + srow * 1024 + ((kc * 2) ^ ((srow & 7) << 4)));
      int key0 = kb * 16 + l15;
      int key1 = key0 + 16;
      half8 b0 = *(const half8*)(ctb + key0 * 1024 + ((kc * 2) ^ ((key0 & 7) << 4)));
      half8 b1 = *(const half8*)(ctb + key1 * 1024 + ((kc * 2) ^ ((key1 & 7) << 4)));
      s0 = __builtin_amdgcn_mfma_f32_16x16x32_f16(a, b0, s0, 0, 0, 0);
      s1 = __builtin_amdgcn_mfma_f32_16x16x32_f16(a, b1, s1, 0, 0, 0);
    }
    const float scale = 0.04419417382415922f;  // 1/sqrt(512)
#pragma unroll
    for (int r = 0; r < 4; ++r) {
      int q = qt * 16 + lq * 4 + r;
      sc[q * 68 + kb * 16 + l15] = s0[r] * scale;
      sc[q * 68 + (kb + 1) * 16 + l15] = s1[r] * scale;
    }
  }
  __syncthreads();

  // ---------- Phase 3a: softmax rows of sc -> P (fp16, swizzled)
  {
    int q = tid >> 3;
    int g = tid & 7;
    const float* row = sc + q * 68 + g * 8;
    float v[8];
#pragma unroll
    for (int i = 0; i < 8; ++i) v[i] = row[i];
    float m = v[0];
#pragma unroll
    for (int i = 1; i < 8; ++i) m = fmaxf(m, v[i]);
    m = fmaxf(m, __shfl_xor(m, 1));
    m = fmaxf(m, __shfl_xor(m, 2));
    m = fmaxf(m, __shfl_xor(m, 4));
    float s = 0.f;
#pragma unroll
    for (int i = 0; i < 8; ++i) { v[i] = __expf(v[i] - m); s += v[i]; }
    s += __shfl_xor(s, 1);
    s += __shfl_xor(s, 2);
    s += __shfl_xor(s, 4);
    float inv = 1.f / s;
    half8 p;
#pragma unroll
    for (int i = 0; i < 8; ++i) p[i] = (_Float16)(v[i] * inv);
    *(half8*)(Pb + q * 128 + ((g * 16) ^ ((q & 7) << 4))) = p;
  }

  // ---------- Phase 3b: transpose ct -> ctT[512][64] into dead xs region
  {
    char* ctTb = (char*)xs;
    int d = tid;
#pragma unroll
    for (int kb2 = 0; kb2 < 8; ++kb2) {
      half8 vv;
#pragma unroll
      for (int j2 = 0; j2 < 8; ++j2) {
        int key = kb2 * 8 + j2;
        vv[j2] = *(const _Float16*)(ctb + key * 1024 + ((2 * d) ^ ((key & 7) << 4)));
      }
      *(half8*)(ctTb + d * 128 + ((kb2 * 16) ^ ((d & 7) << 4))) = vv;
    }
  }
  __syncthreads();

  // ---------- Phase 4: PV  attn[64 q][512 d] = P @ ct, + residual, LN, pool
  f32x4 pacc[4][4];
#pragma unroll
  for (int mi = 0; mi < 4; ++mi)
#pragma unroll
    for (int ni = 0; ni < 4; ++ni) pacc[mi][ni] = fzero;

  {
    char* ctTb = (char*)xs;
#pragma unroll
    for (int ks = 0; ks < 2; ++ks) {
      int kc = ks * 32 + lq * 8;       // key index base
      half8 a[4], b[4];
#pragma unroll
      for (int mi = 0; mi < 4; ++mi) {
        int t = mi * 16 + l15;
        a[mi] = *(const half8*)(Pb + t * 128 + ((kc * 2) ^ ((t & 7) << 4)));
      }
#pragma unroll
      for (int ni = 0; ni < 4; ++ni) {
        int d = w * 64 + ni * 16 + l15;
        b[ni] = *(const half8*)(ctTb + d * 128 + ((kc * 2) ^ ((d & 7) << 4)));
      }
#pragma unroll
      for (int mi = 0; mi < 4; ++mi)
#pragma unroll
        for (int ni = 0; ni < 4; ++ni)
          pacc[mi][ni] = __builtin_amdgcn_mfma_f32_16x16x32_f16(a[mi], b[ni], pacc[mi][ni], 0, 0, 0);
    }
  }

  // residual: v = attn + ct
#pragma unroll
  for (int mi = 0; mi < 4; ++mi)
#pragma unroll
    for (int ni = 0; ni < 4; ++ni)
#pragma unroll
      for (int r = 0; r < 4; ++r) {
        int t = mi * 16 + lq * 4 + r;
        int d = w * 64 + ni * 16 + l15;
        float cv = (float)(*(const _Float16*)(ctb + t * 1024 + ((2 * d) ^ ((t & 7) << 4))));
        pacc[mi][ni][r] += cv;
      }

  // per-row LN statistics: partial sums over this wave's 64 columns
#pragma unroll
  for (int mi = 0; mi < 4; ++mi)
#pragma unroll
    for (int r = 0; r < 4; ++r) {
      float s1 = 0.f, s2 = 0.f;
#pragma unroll
      for (int ni = 0; ni < 4; ++ni) {
        float v = pacc[mi][ni][r];
        s1 += v;
        s2 += v * v;
      }
      s1 += __shfl_xor(s1, 1); s2 += __shfl_xor(s2, 1);
      s1 += __shfl_xor(s1, 2); s2 += __shfl_xor(s2, 2);
      s1 += __shfl_xor(s1, 4); s2 += __shfl_xor(s2, 4);
      s1 += __shfl_xor(s1, 8); s2 += __shfl_xor(s2, 8);
      if (l15 == 0) {
        int t = mi * 16 + lq * 4 + r;
        rowpart[(t * 8 + w) * 2 + 0] = s1;
        rowpart[(t * 8 + w) * 2 + 1] = s2;
      }
    }
  __syncthreads();

  if (tid < 64) {
    float s1 = 0.f, s2 = 0.f;
#pragma unroll
    for (int w2 = 0; w2 < 8; ++w2) {
      s1 += rowpart[(tid * 8 + w2) * 2 + 0];
      s2 += rowpart[(tid * 8 + w2) * 2 + 1];
    }
    float mu = s1 * (1.f / 512.f);
    float var = s2 * (1.f / 512.f) - mu * mu;
    mustat[tid * 2 + 0] = mu;
    mustat[tid * 2 + 1] = rsqrtf(var + 1e-5f);
  }
  __syncthreads();

  // pooled[d] = g[d] * (1/64) * sum_q (v[q][d]-mu[q])*rs[q] + b[d]
#pragma unroll
  for (int ni = 0; ni < 4; ++ni) {
    float s = 0.f;
#pragma unroll
    for (int mi = 0; mi < 4; ++mi)
#pragma unroll
      for (int r = 0; r < 4; ++r) {
        int t = mi * 16 + lq * 4 + r;
        s += (pacc[mi][ni][r] - mustat[t * 2]) * mustat[t * 2 + 1];
      }
    s += __shfl_xor(s, 16);
    s += __shfl_xor(s, 32);
    if (l < 16) {
      int d = w * 64 + ni * 16 + l;
      out[(size_t)blk * 512 + d] = ln_g[d] * (s * (1.f / 64.f)) + ln_b[d];
    }
  }
}

extern "C" void kernel_launch(void* const* d_in, const int* in_sizes, int n_in,
                              void* d_out, int out_size, void* d_ws, size_t ws_size,
                              hipStream_t stream) {
  const float* x      = (const float*)d_in[0];
  const float* conv_w = (const float*)d_in[1];
  const float* conv_b = (const float*)d_in[2];
  const float* ln_g   = (const float*)d_in[3];
  const float* ln_b   = (const float*)d_in[4];
  float* out = (float*)d_out;
  _Float16* Wt = (_Float16*)d_ws;   // 512*1024 fp16 = 1 MB

  prep_w_kernel<<<(HID * HID * 2 + 255) / 256, 256, 0, stream>>>(conv_w, Wt);
  fused_kernel<<<NCHUNK, 512, 0, stream>>>(x, Wt, conv_b, ln_g, ln_b, out);
}

// Round 2
// 226.757 us; speedup vs baseline: 1.5403x; 1.5403x over previous
//
#include <hip/hip_runtime.h>

typedef _Float16 half8 __attribute__((ext_vector_type(8)));
typedef _Float16 half4 __attribute__((ext_vector_type(4)));
typedef float f32x4 __attribute__((ext_vector_type(4)));

#define HID 512
#define NCHUNK 2048

// Repack conv_w [O=512][I=512][tap=2] fp32 -> MFMA-fragment-ordered fp16:
// Wf[((nt*32 + ks)*64 + lane)*8 + j] = W[n = nt*16 + (lane&15)][k = ks*32 + (lane>>4)*8 + j]
// where k = tap*512 + i. One 16x16x32 B-fragment = 1KB contiguous.
__global__ void prep_w_kernel(const float* __restrict__ conv_w, _Float16* __restrict__ Wf) {
  int o = blockIdx.x * blockDim.x + threadIdx.x;
  if (o >= HID * HID * 2) return;
  int j = o & 7;
  int lane = (o >> 3) & 63;
  int ks = (o >> 9) & 31;
  int nt = o >> 14;
  int n = nt * 16 + (lane & 15);
  int k = ks * 32 + (lane >> 4) * 8 + j;
  int tap = k >> 9;
  int i = k & 511;
  Wf[o] = (_Float16)conv_w[n * 1024 + i * 2 + tap];
}

// One block per chunk, 512 threads = 8 waves.
// Row-XOR swizzle on 1KB-row tiles: byte ^= ((row&7)<<4); on 128B-row tiles: same.
__global__ __launch_bounds__(512) void fused_kernel(
    const float* __restrict__ x, const _Float16* __restrict__ Wf,
    const float* __restrict__ conv_b, const float* __restrict__ ln_g,
    const float* __restrict__ ln_b, float* __restrict__ out) {

  // xs: storage row s holds x[s-1]; rows 0 and 65 zero (conv boundary).
  // After scores phase xs is dead -> reused as ctT[512 d][64 key].
  __shared__ __align__(16) _Float16 xs[66 * 512];
  __shared__ __align__(16) _Float16 ct[64 * 512];   // [key][d]
  __shared__ __align__(16) float sc[64 * 64];       // [q][key] scores^T dest, granule-swizzled
  __shared__ __align__(16) _Float16 P[64 * 64];     // [q][key] = softmax + I, swizzled
  __shared__ float rowpart[64 * 8 * 2];
  __shared__ float mustat[64 * 2];

  const int tid = threadIdx.x;
  const int blk = blockIdx.x;
  const int w = tid >> 6;
  const int l = tid & 63;
  const int l15 = l & 15;
  const int lq = l >> 4;
  const int j4 = l15 & 3;

  char* xsb = (char*)xs;
  char* ctb = (char*)ct;
  char* Pb  = (char*)P;
  char* scb = (char*)sc;

  const f32x4 fzero = {0.f, 0.f, 0.f, 0.f};

  // ---- early W prefetch (ks=0,1) — independent of LDS staging
  half8 bA[4], bB[4];
#pragma unroll
  for (int ni = 0; ni < 4; ++ni) {
    bA[ni] = *(const half8*)(Wf + (size_t)(((w * 4 + ni) * 32 + 0) * 64 + l) * 8);
    bB[ni] = *(const half8*)(Wf + (size_t)(((w * 4 + ni) * 32 + 1) * 64 + l) * 8);
  }

  // ---------- Phase 0: stage x chunk -> LDS fp16 (swizzled), zero guard rows
  {
    const float* xg = x + (size_t)blk * (64 * HID);
#pragma unroll
    for (int i = 0; i < 8; ++i) {
      int jj = tid + i * 512;
      int t = jj >> 6;
      int d8 = jj & 63;
      const float4* src = (const float4*)(xg + t * HID + d8 * 8);
      float4 f0 = src[0];
      float4 f1 = src[1];
      half8 h;
      h[0] = (_Float16)f0.x; h[1] = (_Float16)f0.y; h[2] = (_Float16)f0.z; h[3] = (_Float16)f0.w;
      h[4] = (_Float16)f1.x; h[5] = (_Float16)f1.y; h[6] = (_Float16)f1.z; h[7] = (_Float16)f1.w;
      int srow = t + 1;
      *(half8*)(xsb + srow * 1024 + ((d8 * 16) ^ ((srow & 7) << 4))) = h;
    }
    if (tid < 128) {
      int r = (tid < 64) ? 0 : 65;
      int g = tid & 63;
      half8 z = {0, 0, 0, 0, 0, 0, 0, 0};
      *(half8*)(xsb + r * 1024 + g * 16) = z;
    }
  }
  __syncthreads();

  // ---------- Phase 1: conv GEMM ct = relu(A[64x1024] @ W[1024x512] + b)
  // B-frags from global (fragment-ordered Wf), 2-deep register pipeline, no barriers.
  f32x4 acc[4][4];
#pragma unroll
  for (int mi = 0; mi < 4; ++mi)
#pragma unroll
    for (int ni = 0; ni < 4; ++ni) acc[mi][ni] = fzero;

  {
    auto conv_step = [&](int ks, half8* bR) {
      const int kc2 = (ks & 15) * 64 + lq * 16;
      const int rowoff = (ks < 16) ? 0 : 2;
      half8 a[4];
#pragma unroll
      for (int mi = 0; mi < 4; ++mi) {
        int srow = mi * 16 + l15 + rowoff;
        a[mi] = *(const half8*)(xsb + srow * 1024 + (kc2 ^ ((srow & 7) << 4)));
      }
#pragma unroll
      for (int mi = 0; mi < 4; ++mi)
#pragma unroll
        for (int ni = 0; ni < 4; ++ni)
          acc[mi][ni] = __builtin_amdgcn_mfma_f32_16x16x32_f16(a[mi], bR[ni], acc[mi][ni], 0, 0, 0);
    };
    auto loadB = [&](half8* bR, int ks) {
#pragma unroll
      for (int ni = 0; ni < 4; ++ni)
        bR[ni] = *(const half8*)(Wf + (size_t)(((w * 4 + ni) * 32 + ks) * 64 + l) * 8);
    };
    for (int ks = 0; ks < 30; ks += 2) {
      conv_step(ks, bA);
      loadB(bA, ks + 2);
      conv_step(ks + 1, bB);
      loadB(bB, ks + 3);
    }
    conv_step(30, bA);
    conv_step(31, bB);
  }

  // ---------- Phase 1 epilogue: bias+relu (kept in acc), write ct[key][d] packed
  // via in-wave 4x4 transpose across lanes (l15&3).
  {
    float cb[4];
#pragma unroll
    for (int ni = 0; ni < 4; ++ni) cb[ni] = conv_b[w * 64 + ni * 16 + l15];
#pragma unroll
    for (int mi = 0; mi < 4; ++mi)
#pragma unroll
      for (int ni = 0; ni < 4; ++ni) {
        float v0 = fmaxf(acc[mi][ni][0] + cb[ni], 0.f);
        float v1 = fmaxf(acc[mi][ni][1] + cb[ni], 0.f);
        float v2 = fmaxf(acc[mi][ni][2] + cb[ni], 0.f);
        float v3 = fmaxf(acc[mi][ni][3] + cb[ni], 0.f);
        acc[mi][ni][0] = v0; acc[mi][ni][1] = v1;   // keep relu'd for ctT phase
        acc[mi][ni][2] = v2; acc[mi][ni][3] = v3;
        // 4x4 transpose: lane j4 holds col j4 rows 0..3 -> row j4 cols 0..3
        float t0 = __shfl_xor(v1, 1);
        float t1 = __shfl_xor(v0, 1);
        float t2 = __shfl_xor(v3, 1);
        float t3 = __shfl_xor(v2, 1);
        if (j4 & 1) { v0 = t0; v2 = t2; } else { v1 = t1; v3 = t3; }
        float u0 = __shfl_xor(v2, 2);
        float u1 = __shfl_xor(v3, 2);
        float u2 = __shfl_xor(v0, 2);
        float u3 = __shfl_xor(v1, 2);
        if (j4 & 2) { v0 = u0; v1 = u1; } else { v2 = u2; v3 = u3; }
        half4 h = {(_Float16)v0, (_Float16)v1, (_Float16)v2, (_Float16)v3};
        int key = mi * 16 + lq * 4 + j4;
        int dbase = w * 64 + ni * 16 + (l15 & ~3);
        *(half4*)(ctb + key * 1024 + ((dbase * 2) ^ ((key & 7) << 4))) = h;
      }
  }
  __syncthreads();

  // ---------- Phase 2: scores^T[key][q] = (ct @ x^T) / sqrt(D)
  // A = ct[key][d-contig], B = xs[q][d-contig] — both packed b128 reads.
  {
    const int mt = w & 3;
    const int nt0 = (w >> 2) * 2;
    f32x4 s0 = fzero, s1 = fzero;
    for (int ks = 0; ks < 16; ++ks) {
      int kb = ks * 64 + lq * 16;
      int key = mt * 16 + l15;
      half8 a = *(const half8*)(ctb + key * 1024 + (kb ^ ((key & 7) << 4)));
      int q0 = nt0 * 16 + l15;
      int sr0 = q0 + 1, sr1 = q0 + 17;
      half8 b0 = *(const half8*)(xsb + sr0 * 1024 + (kb ^ ((sr0 & 7) << 4)));
      half8 b1 = *(const half8*)(xsb + sr1 * 1024 + (kb ^ ((sr1 & 7) << 4)));
      s0 = __builtin_amdgcn_mfma_f32_16x16x32_f16(a, b0, s0, 0, 0, 0);
      s1 = __builtin_amdgcn_mfma_f32_16x16x32_f16(a, b1, s1, 0, 0, 0);
    }
    const float scale = 0.04419417382415922f;  // 1/sqrt(512)
#pragma unroll
    for (int r = 0; r < 4; ++r) { s0[r] *= scale; s1[r] *= scale; }
    int gran = mt * 4 + lq;
    int q0 = nt0 * 16 + l15, q1 = q0 + 16;
    *(f32x4*)(scb + q0 * 256 + ((gran * 16) ^ ((q0 & 15) << 4))) = s0;
    *(f32x4*)(scb + q1 * 256 + ((gran * 16) ^ ((q1 & 15) << 4))) = s1;
  }
  __syncthreads();

  // ---------- Phase 3a: softmax rows of sc -> P = softmax + I (fp16, swizzled)
  {
    int q = tid >> 3;
    int g = tid & 7;
    f32x4 va = *(const f32x4*)(scb + q * 256 + (((2 * g + 0) * 16) ^ ((q & 15) << 4)));
    f32x4 vb = *(const f32x4*)(scb + q * 256 + (((2 * g + 1) * 16) ^ ((q & 15) << 4)));
    float v[8] = {va[0], va[1], va[2], va[3], vb[0], vb[1], vb[2], vb[3]};
    float m = v[0];
#pragma unroll
    for (int i = 1; i < 8; ++i) m = fmaxf(m, v[i]);
    m = fmaxf(m, __shfl_xor(m, 1));
    m = fmaxf(m, __shfl_xor(m, 2));
    m = fmaxf(m, __shfl_xor(m, 4));
    float s = 0.f;
#pragma unroll
    for (int i = 0; i < 8; ++i) { v[i] = __expf(v[i] - m); s += v[i]; }
    s += __shfl_xor(s, 1);
    s += __shfl_xor(s, 2);
    s += __shfl_xor(s, 4);
    float inv = 1.f / s;
    half8 p;
#pragma unroll
    for (int i = 0; i < 8; ++i) {
      float pv = v[i] * inv + ((g * 8 + i == q) ? 1.f : 0.f);  // +I = fused residual
      p[i] = (_Float16)pv;
    }
    *(half8*)(Pb + q * 128 + ((g * 16) ^ ((q & 7) << 4))) = p;
  }

  // ---------- Phase 3b: write ctT[512 d][64 key] into dead xs region from live acc
  {
    char* ctTb = xsb;
#pragma unroll
    for (int mi = 0; mi < 4; ++mi)
#pragma unroll
      for (int ni = 0; ni < 4; ++ni) {
        int t0 = mi * 16 + lq * 4;
        int d = w * 64 + ni * 16 + l15;
        half4 h = {(_Float16)acc[mi][ni][0], (_Float16)acc[mi][ni][1],
                   (_Float16)acc[mi][ni][2], (_Float16)acc[mi][ni][3]};
        *(half4*)(ctTb + d * 128 + ((t0 * 2) ^ ((d & 7) << 4))) = h;
      }
  }
  __syncthreads();

  // ---------- Phase 4: attn+ct = (P+I) @ ct  -> pacc[q][d], then LN stats + pool
  f32x4 pacc[4][4];
#pragma unroll
  for (int mi = 0; mi < 4; ++mi)
#pragma unroll
    for (int ni = 0; ni < 4; ++ni) pacc[mi][ni] = fzero;

  {
    char* ctTb = xsb;
#pragma unroll
    for (int ks = 0; ks < 2; ++ks) {
      half8 a[4], b[4];
#pragma unroll
      for (int mi = 0; mi < 4; ++mi) {
        int q = mi * 16 + l15;
        a[mi] = *(const half8*)(Pb + q * 128 + (((ks * 4 + lq) * 16) ^ ((q & 7) << 4)));
      }
#pragma unroll
      for (int ni = 0; ni < 4; ++ni) {
        int d = w * 64 + ni * 16 + l15;
        b[ni] = *(const half8*)(ctTb + d * 128 + (((ks * 4 + lq) * 16) ^ ((d & 7) << 4)));
      }
#pragma unroll
      for (int mi = 0; mi < 4; ++mi)
#pragma unroll
        for (int ni = 0; ni < 4; ++ni)
          pacc[mi][ni] = __builtin_amdgcn_mfma_f32_16x16x32_f16(a[mi], b[ni], pacc[mi][ni], 0, 0, 0);
    }
  }

  // per-row LN partial sums over this wave's 64 d-columns
#pragma unroll
  for (int mi = 0; mi < 4; ++mi)
#pragma unroll
    for (int r = 0; r < 4; ++r) {
      float s1 = 0.f, s2 = 0.f;
#pragma unroll
      for (int ni = 0; ni < 4; ++ni) {
        float v = pacc[mi][ni][r];
        s1 += v;
        s2 += v * v;
      }
      s1 += __shfl_xor(s1, 1); s2 += __shfl_xor(s2, 1);
      s1 += __shfl_xor(s1, 2); s2 += __shfl_xor(s2, 2);
      s1 += __shfl_xor(s1, 4); s2 += __shfl_xor(s2, 4);
      s1 += __shfl_xor(s1, 8); s2 += __shfl_xor(s2, 8);
      if (l15 == 0) {
        int t = mi * 16 + lq * 4 + r;
        rowpart[(t * 8 + w) * 2 + 0] = s1;
        rowpart[(t * 8 + w) * 2 + 1] = s2;
      }
    }
  __syncthreads();

  if (tid < 64) {
    float s1 = 0.f, s2 = 0.f;
#pragma unroll
    for (int w2 = 0; w2 < 8; ++w2) {
      s1 += rowpart[(tid * 8 + w2) * 2 + 0];
      s2 += rowpart[(tid * 8 + w2) * 2 + 1];
    }
    float mu = s1 * (1.f / 512.f);
    float var = s2 * (1.f / 512.f) - mu * mu;
    mustat[tid * 2 + 0] = mu;
    mustat[tid * 2 + 1] = rsqrtf(var + 1e-5f);
  }
  __syncthreads();

  // pooled[d] = g[d] * (1/64) * sum_q (v[q][d]-mu[q])*rs[q] + b[d]
#pragma unroll
  for (int ni = 0; ni < 4; ++ni) {
    float s = 0.f;
#pragma unroll
    for (int mi = 0; mi < 4; ++mi)
#pragma unroll
      for (int r = 0; r < 4; ++r) {
        int t = mi * 16 + lq * 4 + r;
        s += (pacc[mi][ni][r] - mustat[t * 2]) * mustat[t * 2 + 1];
      }
    s += __shfl_xor(s, 16);
    s += __shfl_xor(s, 32);
    if (l < 16) {
      int d = w * 64 + ni * 16 + l;
      out[(size_t)blk * 512 + d] = ln_g[d] * (s * (1.f / 64.f)) + ln_b[d];
    }
  }
}

extern "C" void kernel_launch(void* const* d_in, const int* in_sizes, int n_in,
                              void* d_out, int out_size, void* d_ws, size_t ws_size,
                              hipStream_t stream) {
  const float* x      = (const float*)d_in[0];
  const float* conv_w = (const float*)d_in[1];
  const float* conv_b = (const float*)d_in[2];
  const float* ln_g   = (const float*)d_in[3];
  const float* ln_b   = (const float*)d_in[4];
  float* out = (float*)d_out;
  _Float16* Wf = (_Float16*)d_ws;   // 512*1024 fp16 = 1 MB, fragment-ordered

  prep_w_kernel<<<(HID * HID * 2 + 255) / 256, 256, 0, stream>>>(conv_w, Wf);
  fused_kernel<<<NCHUNK, 512, 0, stream>>>(x, Wf, conv_b, ln_g, ln_b, out);
}